// Round 1
// baseline (331.574 us; speedup 1.0000x reference)
//
#include <hip/hip_runtime.h>
#include <hip/hip_bf16.h>
#include <stdint.h>

// Top-k (k = 10% of N) by value over flat fp32, scatter values to positions,
// zeros elsewhere. Strategy: radix-select exact 32-bit threshold via
// histograms (2 or 3 read passes) + one dense compare/scatter pass.
// Exact tie handling at the threshold value: select equal elements with the
// SMALLEST indices (jax.lax.top_k stable tie-break).

#define STREAM_GRID 1024
#define STREAM_BLK  256
#define EQ_CAP      65536

// ---- scalars layout in ws ----
// sc[0] = prefix (determined high bits of threshold, in place)
// sc[1] = k_rem  (elements still needed among prefix-matching)
// sc[2] = t_u    (final exact threshold, sortable-u32 space)
// sc[3] = need_eq (# of ==t_u elements to include)
// sc[4] = eq_count (atomic)

__device__ __forceinline__ unsigned int f2u(float x) {
    unsigned int b = __float_as_uint(x);
    return (b & 0x80000000u) ? ~b : (b | 0x80000000u);
}

__global__ void init_kernel(unsigned int* sc, unsigned int k) {
    if (threadIdx.x == 0) {
        sc[0] = 0u; sc[1] = k; sc[2] = 0u; sc[3] = 0u; sc[4] = 0u;
    }
}

// Histogram with per-wave-privatized LDS copies. Optional prefix filter:
// element participates iff (u >> match_shift) == (sc[0] >> match_shift).
// match_shift >= 32 means "no filter".
__global__ void __launch_bounds__(256)
hist_lds_kernel(const float* __restrict__ x, int n4, long long N,
                unsigned int* __restrict__ hist,
                const unsigned int* __restrict__ sc,
                int nbins, int shift, int match_shift)
{
    __shared__ unsigned int lh[4][2048];
    int tid = threadIdx.x;
    for (int i = tid; i < 4 * 2048; i += 256) ((unsigned int*)lh)[i] = 0u;
    const bool filt = (match_shift < 32);
    const int ms = filt ? match_shift : 0;
    unsigned int pref = 0u;
    if (filt) pref = sc[0] >> ms;
    __syncthreads();
    unsigned int* my = lh[tid >> 6];
    const float4* x4 = (const float4*)x;
    const unsigned int mask = (unsigned int)nbins - 1u;
    int stride = gridDim.x * blockDim.x;
    for (int i = blockIdx.x * blockDim.x + tid; i < n4; i += stride) {
        float4 v = x4[i];
        unsigned int u;
        u = f2u(v.x); if (!filt || ((u >> ms) == pref)) atomicAdd(&my[(u >> shift) & mask], 1u);
        u = f2u(v.y); if (!filt || ((u >> ms) == pref)) atomicAdd(&my[(u >> shift) & mask], 1u);
        u = f2u(v.z); if (!filt || ((u >> ms) == pref)) atomicAdd(&my[(u >> shift) & mask], 1u);
        u = f2u(v.w); if (!filt || ((u >> ms) == pref)) atomicAdd(&my[(u >> shift) & mask], 1u);
    }
    // tail (N not multiple of 4)
    long long t0 = (long long)n4 * 4;
    if (blockIdx.x == 0 && tid < (int)(N - t0)) {
        unsigned int u = f2u(x[t0 + tid]);
        if (!filt || ((u >> ms) == pref)) atomicAdd(&my[(u >> shift) & mask], 1u);
    }
    __syncthreads();
    for (int i = tid; i < nbins; i += 256) {
        unsigned int s = lh[0][i] + lh[1][i] + lh[2][i] + lh[3][i];
        if (s) atomicAdd(&hist[i], s);
    }
}

// Plan A pass 2: histogram low 21 bits of elements whose top 11 bits match.
__global__ void __launch_bounds__(256)
hist21_kernel(const float* __restrict__ x, int n4, long long N,
              unsigned int* __restrict__ hist2,
              const unsigned int* __restrict__ sc)
{
    unsigned int b1 = sc[0] >> 21;
    const float4* x4 = (const float4*)x;
    int stride = gridDim.x * blockDim.x;
    for (int i = blockIdx.x * blockDim.x + threadIdx.x; i < n4; i += stride) {
        float4 v = x4[i];
        unsigned int u;
        u = f2u(v.x); if ((u >> 21) == b1) atomicAdd(&hist2[u & 0x1FFFFFu], 1u);
        u = f2u(v.y); if ((u >> 21) == b1) atomicAdd(&hist2[u & 0x1FFFFFu], 1u);
        u = f2u(v.z); if ((u >> 21) == b1) atomicAdd(&hist2[u & 0x1FFFFFu], 1u);
        u = f2u(v.w); if ((u >> 21) == b1) atomicAdd(&hist2[u & 0x1FFFFFu], 1u);
    }
    long long t0 = (long long)n4 * 4;
    if (blockIdx.x == 0 && threadIdx.x < (int)(N - t0)) {
        unsigned int u = f2u(x[t0 + threadIdx.x]);
        if ((u >> 21) == b1) atomicAdd(&hist2[u & 0x1FFFFFu], 1u);
    }
}

__device__ __forceinline__ unsigned int block_exscan256(unsigned int v,
                                                        volatile unsigned int* lds,
                                                        int tid)
{
    lds[tid] = v;
    __syncthreads();
    for (int off = 1; off < 256; off <<= 1) {
        unsigned int t = (tid >= off) ? lds[tid - off] : 0u;
        __syncthreads();
        lds[tid] += t;
        __syncthreads();
    }
    unsigned int incl = lds[tid];
    return incl - v;
}

// Generic single-block descending scan over nbins (<=2048, multiple of 256).
// Finds bin b such that count_above(b) < k_rem <= count_above(b)+hist[b].
// Non-final: extend prefix + update k_rem. Final: set t_u and need_eq.
// Zeros hist afterwards so it can be reused by the next level.
__global__ void __launch_bounds__(256)
scan_kernel(unsigned int* __restrict__ hist, int nbins, int shift, int is_final,
            unsigned int* __restrict__ sc)
{
    __shared__ unsigned int lds[256];
    int tid = threadIdx.x;
    int seg = nbins >> 8;
    unsigned int prefix = sc[0];
    unsigned int krem = sc[1];
    unsigned int loc[8];
    unsigned int partial = 0u;
    for (int i = 0; i < seg; ++i) {
        int p = tid * seg + i;
        unsigned int v = hist[nbins - 1 - p];
        loc[i] = v; partial += v;
    }
    unsigned int cum = block_exscan256(partial, lds, tid);
    for (int i = 0; i < seg; ++i) {
        int p = tid * seg + i;
        int bin = nbins - 1 - p;
        unsigned int c = loc[i];
        if (cum < krem && cum + c >= krem) {
            if (is_final) { sc[2] = prefix | ((unsigned int)bin << shift); sc[3] = krem - cum; }
            else          { sc[0] = prefix | ((unsigned int)bin << shift); sc[1] = krem - cum; }
        }
        cum += c;
    }
    for (int i = 0; i < seg; ++i) hist[nbins - 1 - (tid * seg + i)] = 0u;
}

// Plan A hierarchical scan helpers over 2^21 bins.
__global__ void __launch_bounds__(256)
chunksum_kernel(const unsigned int* __restrict__ hist2, unsigned int* __restrict__ chunk_sums)
{
    __shared__ unsigned int p[256];
    int tid = threadIdx.x;
    int chunk = blockIdx.x;
    const unsigned int* base = hist2 + (size_t)chunk * 1024;
    unsigned int s = 0u;
    for (int i = tid; i < 1024; i += 256) s += base[i];
    p[tid] = s;
    __syncthreads();
    for (int off = 128; off; off >>= 1) {
        if (tid < off) p[tid] += p[tid + off];
        __syncthreads();
    }
    if (tid == 0) chunk_sums[chunk] = p[0];
}

__global__ void __launch_bounds__(256)
scanA_final_kernel(const unsigned int* __restrict__ hist2,
                   const unsigned int* __restrict__ chunk_sums,
                   unsigned int* __restrict__ sc)
{
    __shared__ unsigned int lds[256];
    __shared__ unsigned int s_c, s_krem2;
    int tid = threadIdx.x;
    unsigned int prefix = sc[0];
    unsigned int krem = sc[1];
    // phase 1: 2048 chunks, descending, 8 per thread
    unsigned int loc[8];
    unsigned int partial = 0u;
    for (int i = 0; i < 8; ++i) {
        int p = tid * 8 + i;
        unsigned int v = chunk_sums[2047 - p];
        loc[i] = v; partial += v;
    }
    unsigned int cum = block_exscan256(partial, lds, tid);
    for (int i = 0; i < 8; ++i) {
        int p = tid * 8 + i;
        int chunk = 2047 - p;
        unsigned int c = loc[i];
        if (cum < krem && cum + c >= krem) { s_c = (unsigned int)chunk; s_krem2 = krem - cum; }
        cum += c;
    }
    __syncthreads();
    unsigned int c = s_c;
    unsigned int krem2 = s_krem2;
    // phase 2: 1024 bins in chunk c, descending, 4 per thread
    unsigned int loc2[4];
    partial = 0u;
    for (int i = 0; i < 4; ++i) {
        int p = tid * 4 + i;
        unsigned int v = hist2[(size_t)c * 1024 + (1023 - p)];
        loc2[i] = v; partial += v;
    }
    __syncthreads();
    unsigned int cum2 = block_exscan256(partial, lds, tid);
    for (int i = 0; i < 4; ++i) {
        int p = tid * 4 + i;
        int bin = 1023 - p;
        unsigned int cc = loc2[i];
        if (cum2 < krem2 && cum2 + cc >= krem2) {
            sc[2] = prefix | (c * 1024u + (unsigned int)bin);
            sc[3] = krem2 - cum2;
        }
        cum2 += cc;
    }
}

__global__ void __launch_bounds__(256)
scatter_kernel(const float* __restrict__ x, int n4, long long N,
               float* __restrict__ out,
               unsigned int* __restrict__ sc,
               unsigned int* __restrict__ eq_list, int cap)
{
    unsigned int tu = sc[2];
    const float4* x4 = (const float4*)x;
    float4* o4 = (float4*)out;
    int stride = gridDim.x * blockDim.x;
    for (int i = blockIdx.x * blockDim.x + threadIdx.x; i < n4; i += stride) {
        float4 v = x4[i];
        unsigned int u0 = f2u(v.x), u1 = f2u(v.y), u2 = f2u(v.z), u3 = f2u(v.w);
        float4 o;
        o.x = (u0 > tu) ? v.x : 0.0f;
        o.y = (u1 > tu) ? v.y : 0.0f;
        o.z = (u2 > tu) ? v.z : 0.0f;
        o.w = (u3 > tu) ? v.w : 0.0f;
        if (u0 == tu || u1 == tu || u2 == tu || u3 == tu) { // extremely rare
            unsigned int b = (unsigned int)i * 4u;
            if (u0 == tu) { unsigned int p = atomicAdd(&sc[4], 1u); if (p < (unsigned int)cap) eq_list[p] = b + 0u; }
            if (u1 == tu) { unsigned int p = atomicAdd(&sc[4], 1u); if (p < (unsigned int)cap) eq_list[p] = b + 1u; }
            if (u2 == tu) { unsigned int p = atomicAdd(&sc[4], 1u); if (p < (unsigned int)cap) eq_list[p] = b + 2u; }
            if (u3 == tu) { unsigned int p = atomicAdd(&sc[4], 1u); if (p < (unsigned int)cap) eq_list[p] = b + 3u; }
        }
        o4[i] = o;
    }
    long long t0 = (long long)n4 * 4;
    if (blockIdx.x == 0 && threadIdx.x < (int)(N - t0)) {
        long long idx = t0 + threadIdx.x;
        float v = x[idx];
        unsigned int u = f2u(v);
        out[idx] = (u > tu) ? v : 0.0f;
        if (u == tu) { unsigned int p = atomicAdd(&sc[4], 1u); if (p < (unsigned int)cap) eq_list[p] = (unsigned int)idx; }
    }
}

// Among elements exactly equal to t_u, write the value at the need_eq
// SMALLEST indices (stable tie-break, matching jax.lax.top_k).
__global__ void __launch_bounds__(256)
eqfix_kernel(float* __restrict__ out, const unsigned int* __restrict__ sc,
             const unsigned int* __restrict__ eq_list, int cap)
{
    unsigned int m = sc[4];
    if (m > (unsigned int)cap) m = (unsigned int)cap;
    unsigned int need = sc[3];
    unsigned int tu = sc[2];
    float f = __uint_as_float((tu & 0x80000000u) ? (tu & 0x7FFFFFFFu) : ~tu);
    for (unsigned int j = threadIdx.x; j < m; j += blockDim.x) {
        unsigned int idx = eq_list[j];
        unsigned int cnt = 0u;
        for (unsigned int l = 0; l < m; ++l) cnt += (eq_list[l] < idx) ? 1u : 0u;
        if (cnt < need) out[idx] = f;
    }
}

extern "C" void kernel_launch(void* const* d_in, const int* in_sizes, int n_in,
                              void* d_out, int out_size, void* d_ws, size_t ws_size,
                              hipStream_t stream) {
    const float* x = (const float*)d_in[0];
    float* out = (float*)d_out;
    long long N = (long long)in_sizes[0];
    int n4 = (int)(N >> 2);
    unsigned int k = (unsigned int)((double)N * 0.1);
    if (k == 0u) k = 1u;

    uint8_t* w = (uint8_t*)d_ws;
    unsigned int* sc         = (unsigned int*)(w);                       // 64 B
    unsigned int* hist1      = (unsigned int*)(w + 256);                 // 8 KB
    unsigned int* chunk_sums = (unsigned int*)(w + 256 + 8192);          // 8 KB
    unsigned int* eq_list    = (unsigned int*)(w + 256 + 16384);         // 256 KB
    size_t baseB = 256 + 16384 + 262144;
    unsigned int* hist2      = (unsigned int*)(w + baseB);               // 8 MB (plan A)
    size_t needA = baseB + ((size_t)1 << 21) * sizeof(unsigned int);
    bool planA = (ws_size >= needA);

    int grid = STREAM_GRID;

    hipMemsetAsync(hist1, 0, 2048 * sizeof(unsigned int), stream);
    init_kernel<<<1, 64, 0, stream>>>(sc, k);

    if (planA) {
        hipMemsetAsync(hist2, 0, ((size_t)1 << 21) * sizeof(unsigned int), stream);
        // level 0: top 11 bits
        hist_lds_kernel<<<grid, STREAM_BLK, 0, stream>>>(x, n4, N, hist1, sc, 2048, 21, 32);
        scan_kernel<<<1, 256, 0, stream>>>(hist1, 2048, 21, 0, sc);
        // level 1: low 21 bits, filtered
        hist21_kernel<<<grid, STREAM_BLK, 0, stream>>>(x, n4, N, hist2, sc);
        chunksum_kernel<<<2048, 256, 0, stream>>>(hist2, chunk_sums);
        scanA_final_kernel<<<1, 256, 0, stream>>>(hist2, chunk_sums, sc);
    } else {
        // 3-level fallback: 11 + 11 + 10 bits, hist reused (scan zeroes it)
        hist_lds_kernel<<<grid, STREAM_BLK, 0, stream>>>(x, n4, N, hist1, sc, 2048, 21, 32);
        scan_kernel<<<1, 256, 0, stream>>>(hist1, 2048, 21, 0, sc);
        hist_lds_kernel<<<grid, STREAM_BLK, 0, stream>>>(x, n4, N, hist1, sc, 2048, 10, 21);
        scan_kernel<<<1, 256, 0, stream>>>(hist1, 2048, 10, 0, sc);
        hist_lds_kernel<<<grid, STREAM_BLK, 0, stream>>>(x, n4, N, hist1, sc, 1024, 0, 10);
        scan_kernel<<<1, 256, 0, stream>>>(hist1, 1024, 0, 1, sc);
    }

    scatter_kernel<<<grid, STREAM_BLK, 0, stream>>>(x, n4, N, out, sc, eq_list, EQ_CAP);
    eqfix_kernel<<<1, 256, 0, stream>>>(out, sc, eq_list, EQ_CAP);
}